// Round 10
// baseline (276.397 us; speedup 1.0000x reference)
//
#include <hip/hip_runtime.h>
#include <hip/hip_bf16.h>
#include <math.h>

#define D_MODEL 1024
#define D_STATE 16
#define D_CONV  4
#define D_INNER 2048
#define BATCH   2
#define SEQ     2048
#define M_TOTAL (BATCH*SEQ)   // 4096
#define DT_VAL  0.1f

// scan chunking: 32 chunks of 64 outputs, 64 warmup steps (dA^64 <= 1.7e-3)
#define CHUNK 64
#define WARM  64
#define NCHUNK (SEQ / CHUNK)  // 32
#define TSTEP 8               // x/z tile depth staged through LDS

typedef __attribute__((ext_vector_type(8))) __bf16 bf16x8;
typedef __attribute__((ext_vector_type(4))) __bf16 bf16x4;
typedef __attribute__((ext_vector_type(4))) float floatx4;

// async global->LDS, 16 B per lane. LDS dest must be uniform base + lane*16B
// (our grow/gcol order satisfies this per 32-wide panel; see m97/m104 notes).
__device__ __forceinline__ void gld_lds16(const __bf16* g, __bf16* l) {
    __builtin_amdgcn_global_load_lds(
        (const __attribute__((address_space(1))) void*)g,
        (__attribute__((address_space(3))) void*)l, 16, 0, 0);
}

// ---------------------------------------------------------------------------
// NT GEMM, bf16 inputs: C[m][n] = sum_k A[m][k]*W[n][k].
// 128x128 tile. Single-barrier double-buffered K-loop (BK=32 per stage):
//   barrier -> issue async loads for tile k+1 into buf^1 -> compute tile k.
// The vmcnt(0) drain at the barrier now waits on loads that had the whole
// previous compute phase in flight (was: issued-then-immediately-drained).
// Strides/extents are template constants (strength-reduced addressing).
// Block swizzle: bid&7 = XCD group -> 4 consecutive M-stripes (L2 reuse).
// EPI 1 (in_proj): n0<2048 -> O1 = bf16(acc); n0>=2048 -> O2 = bf16(silu(acc)).
// EPI 2 (out_proj, split-K=4): plain stores; ks 0,1 -> Cf, ks 2,3 -> Cf2.
// Occupancy note: 32 KB LDS + ~88 VGPR keeps 4+ blocks/CU (round-8 fat tile
// at 48 KB/168 VGPR regressed 60->93 us — occupancy beats per-block reuse).
// ---------------------------------------------------------------------------
template<int EPI, int LDA, int LDW, int KLEN, int NBX>
__global__ __launch_bounds__(256) void gemm_v6(
    const __bf16* __restrict__ A, const __bf16* __restrict__ W,
    float* __restrict__ Cf, float* __restrict__ Cf2, int ldc,
    __bf16* __restrict__ O1, __bf16* __restrict__ O2)
{
    __shared__ __bf16 As[2][128][32];   // 16 KB (double buffer)
    __shared__ __bf16 Bs[2][128][32];   // 16 KB

    const int tid  = threadIdx.x;
    const int bid  = blockIdx.x;
    const int xcd  = bid & 7;
    const int i    = bid >> 3;
    const int byl  = i & 3;
    const int rest = i >> 2;
    const int bx   = rest % NBX;
    const int ks   = rest / NBX;
    const int m0   = (xcd * 4 + byl) * 128;
    const int n0   = bx * 128;
    const int koff = ks * KLEN;

    const int wave = tid >> 6;
    const int lane = tid & 63;
    const int wr   = (wave >> 1) << 6;
    const int wc   = (wave & 1) << 6;
    const int fm   = lane & 15;
    const int fk   = (lane >> 4) << 3;
    const int grow = lane >> 2;
    const int gcol = (lane & 3) << 3;
    const int arow = wave * 16 + grow;   // staging row (this thread)

    floatx4 acc[4][4];
    #pragma unroll
    for (int a = 0; a < 4; ++a)
        #pragma unroll
        for (int b = 0; b < 4; ++b)
            acc[a][b] = (floatx4){0.f, 0.f, 0.f, 0.f};

    const __bf16* ap = A + (size_t)(m0 + arow) * LDA + koff + gcol;
    const __bf16* wp = W + (size_t)(n0 + arow) * LDW + koff + gcol;

    constexpr int NKIT = KLEN / 32;

    // preload tile 0 -> buf 0
    gld_lds16(ap,                     &As[0][arow][gcol]);
    gld_lds16(ap + (size_t)64 * LDA,  &As[0][arow + 64][gcol]);
    gld_lds16(wp,                     &Bs[0][arow][gcol]);
    gld_lds16(wp + (size_t)64 * LDW,  &Bs[0][arow + 64][gcol]);

    #pragma unroll 2
    for (int kit = 0; kit < NKIT; ++kit) {
        const int buf = kit & 1;
        __syncthreads();   // drains stage into buf; ends prior reads of buf^1
        if (kit + 1 < NKIT) {
            const int k1 = (kit + 1) * 32;
            gld_lds16(ap + k1,                    &As[buf ^ 1][arow][gcol]);
            gld_lds16(ap + k1 + (size_t)64 * LDA, &As[buf ^ 1][arow + 64][gcol]);
            gld_lds16(wp + k1,                    &Bs[buf ^ 1][arow][gcol]);
            gld_lds16(wp + k1 + (size_t)64 * LDW, &Bs[buf ^ 1][arow + 64][gcol]);
        }
        bf16x8 af[4], bfv[4];
        #pragma unroll
        for (int a = 0; a < 4; ++a)
            af[a] = *(bf16x8*)&As[buf][wr + a * 16 + fm][fk];
        #pragma unroll
        for (int b = 0; b < 4; ++b)
            bfv[b] = *(bf16x8*)&Bs[buf][wc + b * 16 + fm][fk];
        #pragma unroll
        for (int a = 0; a < 4; ++a)
            #pragma unroll
            for (int b = 0; b < 4; ++b)
                acc[a][b] = __builtin_amdgcn_mfma_f32_16x16x32_bf16(
                    af[a], bfv[b], acc[a][b], 0, 0, 0);
    }

    // epilogue: C/D layout col=lane&15, row=(lane>>4)*4+reg
    const int crow = (lane >> 4) << 2;
    const int ccol = lane & 15;
    #pragma unroll
    for (int a = 0; a < 4; ++a) {
        #pragma unroll
        for (int b = 0; b < 4; ++b) {
            const int cm = m0 + wr + a * 16 + crow;
            const int cn = n0 + wc + b * 16 + ccol;
            #pragma unroll
            for (int r = 0; r < 4; ++r) {
                const float v = acc[a][b][r];
                if (EPI == 1) {
                    if (n0 < 2048) {
                        O1[(size_t)(cm + r) * 2048 + cn] = (__bf16)v;
                    } else {
                        const float s = v / (1.f + __expf(-v));
                        O2[(size_t)(cm + r) * 2048 + cn - 2048] = (__bf16)s;
                    }
                } else {
                    float* dst = (ks < 2 ? Cf : Cf2) +
                                 (size_t)(ks & 1) * M_TOTAL * ldc;
                    dst[(size_t)(cm + r) * ldc + cn] = v;
                }
            }
        }
    }
}

// ---------------------------------------------------------------------------
// Reduce split-K=4 partials: out = (p0+p1) + (p2+p3).
// ---------------------------------------------------------------------------
__global__ __launch_bounds__(256) void reduce4(
    const float* __restrict__ p01, const float* __restrict__ p23,
    float* __restrict__ out)
{
    const size_t i = (size_t)(blockIdx.x * 256 + threadIdx.x) * 4;
    const float4 a = *(const float4*)(p01 + i);
    const float4 b = *(const float4*)(p01 + (size_t)M_TOTAL * D_MODEL + i);
    const float4 c = *(const float4*)(p23 + i);
    const float4 d = *(const float4*)(p23 + (size_t)M_TOTAL * D_MODEL + i);
    float4 o;
    o.x = (a.x + b.x) + (c.x + d.x);
    o.y = (a.y + b.y) + (c.y + d.y);
    o.z = (a.z + b.z) + (c.z + d.z);
    o.w = (a.w + b.w) + (c.w + d.w);
    *(float4*)(out + i) = o;
}

// ---------------------------------------------------------------------------
// x_proj as MFMA GEMM: bc[m][j] += sum_k xsc[m][k] * wp[j][k], j in 0..31.
// 128-row m-tile, split-K=8 (k-chunk 256), 32x8 = 256 blocks.
// ---------------------------------------------------------------------------
__global__ __launch_bounds__(256) void xproj_mfma(
    const __bf16* __restrict__ X, const __bf16* __restrict__ Wp,
    float* __restrict__ bc)
{
    __shared__ __bf16 Ash[128][32];    // 8 KB, unpadded
    __shared__ __bf16 Wsh[32][264];    // 16.5 KB; stride 264 -> 2-way max

    const int tid  = threadIdx.x;
    const int bid  = blockIdx.x;
    const int ks   = bid & 7;
    const int mb   = bid >> 3;
    const int m0   = mb * 128;
    const int koff = ks * 256;
    const int wave = tid >> 6;
    const int lane = tid & 63;
    const int fm   = lane & 15;
    const int fk   = (lane >> 4) << 3;
    const int grow = lane >> 2;
    const int gcol = (lane & 3) << 3;

    {
        const int r = tid >> 3;
        const int c = (tid & 7) << 5;
        #pragma unroll
        for (int q = 0; q < 4; ++q)
            *(bf16x8*)&Wsh[r][c + q * 8] =
                *(const bf16x8*)(Wp + (size_t)r * D_INNER + koff + c + q * 8);
    }

    floatx4 acc[2][2];
    #pragma unroll
    for (int a = 0; a < 2; ++a)
        #pragma unroll
        for (int b = 0; b < 2; ++b)
            acc[a][b] = (floatx4){0.f, 0.f, 0.f, 0.f};

    for (int kit = 0; kit < 8; ++kit) {
        const int kg = koff + kit * 32;
        __syncthreads();
        #pragma unroll
        for (int issue = 0; issue < 2; ++issue) {
            const int r = issue * 64 + wave * 16 + grow;
            gld_lds16(X + (size_t)(m0 + r) * D_INNER + kg + gcol, &Ash[r][gcol]);
        }
        __syncthreads();

        bf16x8 af[2], wf[2];
        af[0] = *(bf16x8*)&Ash[wave * 32 + fm][fk];
        af[1] = *(bf16x8*)&Ash[wave * 32 + 16 + fm][fk];
        wf[0] = *(bf16x8*)&Wsh[fm][kit * 32 + fk];
        wf[1] = *(bf16x8*)&Wsh[16 + fm][kit * 32 + fk];
        #pragma unroll
        for (int a = 0; a < 2; ++a)
            #pragma unroll
            for (int b = 0; b < 2; ++b)
                acc[a][b] = __builtin_amdgcn_mfma_f32_16x16x32_bf16(
                    af[a], wf[b], acc[a][b], 0, 0, 0);
    }

    const int crow = (lane >> 4) << 2;
    const int ccol = lane & 15;
    #pragma unroll
    for (int a = 0; a < 2; ++a)
        #pragma unroll
        for (int b = 0; b < 2; ++b)
            #pragma unroll
            for (int r = 0; r < 4; ++r)
                atomicAdd(bc + (size_t)(m0 + wave * 32 + a * 16 + crow + r) * 32
                             + b * 16 + ccol, acc[a][b][r]);
}

// ---------------------------------------------------------------------------
// Cast x, in_proj_w, out_proj_w, x_proj_w to bf16 AND zero bcbuf, one kernel.
// ---------------------------------------------------------------------------
__global__ __launch_bounds__(256) void cast5(
    const float* __restrict__ x, const float* __restrict__ win,
    const float* __restrict__ wout, const float* __restrict__ xpw,
    __bf16* __restrict__ xbf, __bf16* __restrict__ winbf,
    __bf16* __restrict__ woutbf, __bf16* __restrict__ xpwbf,
    float* __restrict__ bcz)
{
    const size_t g = (size_t)(blockIdx.x * 256 + threadIdx.x);
    if (g >= 2637824) {   // zero segment: bcbuf (131072 floats)
        const size_t off = (g - 2637824) * 4;
        *(float4*)(bcz + off) = (float4){0.f, 0.f, 0.f, 0.f};
        return;
    }
    const size_t j = g * 4;
    const float* src; __bf16* dst; size_t off;
    if (j < 4194304)       { src = x;    dst = xbf;    off = j; }
    else if (j < 8388608)  { src = win;  dst = winbf;  off = j - 4194304; }
    else if (j < 10485760) { src = wout; dst = woutbf; off = j - 8388608; }
    else                   { src = xpw;  dst = xpwbf;  off = j - 10485760; }
    const float4 v = *(const float4*)(src + off);
    bf16x4 o;
    o[0] = (__bf16)v.x; o[1] = (__bf16)v.y; o[2] = (__bf16)v.z; o[3] = (__bf16)v.w;
    *(bf16x4*)(dst + off) = o;
}

// ---------------------------------------------------------------------------
// Depthwise causal conv (k=4) + bias + SiLU. Reads xsp bf16 (ld=2048),
// writes xsc bf16 (scan + xproj input).
// ---------------------------------------------------------------------------
__global__ __launch_bounds__(256) void conv_silu(
    const __bf16* __restrict__ xsp, const float* __restrict__ cw,
    const float* __restrict__ cb, __bf16* __restrict__ xsc)
{
    const int g  = blockIdx.x * 256 + threadIdx.x;
    const int d4 = g & (D_INNER / 4 - 1);
    const int m  = g >> 9;
    const int l  = m & (SEQ - 1);
    const int d  = d4 << 2;

    const float4 w0 = *(const float4*)(cw + (size_t)(d + 0) * 4);
    const float4 w1 = *(const float4*)(cw + (size_t)(d + 1) * 4);
    const float4 w2 = *(const float4*)(cw + (size_t)(d + 2) * 4);
    const float4 w3 = *(const float4*)(cw + (size_t)(d + 3) * 4);
    const float4 bv = *(const float4*)(cb + d);
    float a0 = bv.x, a1 = bv.y, a2 = bv.z, a3 = bv.w;

    #pragma unroll
    for (int j = 0; j < 4; ++j) {
        if (l + j >= 3) {
            const bf16x4 v = *(const bf16x4*)(xsp + (size_t)(m + j - 3) * D_INNER + d);
            const float wj0 = (j==0)?w0.x:(j==1)?w0.y:(j==2)?w0.z:w0.w;
            const float wj1 = (j==0)?w1.x:(j==1)?w1.y:(j==2)?w1.z:w1.w;
            const float wj2 = (j==0)?w2.x:(j==1)?w2.y:(j==2)?w2.z:w2.w;
            const float wj3 = (j==0)?w3.x:(j==1)?w3.y:(j==2)?w3.z:w3.w;
            a0 = fmaf(wj0, (float)v[0], a0);
            a1 = fmaf(wj1, (float)v[1], a1);
            a2 = fmaf(wj2, (float)v[2], a2);
            a3 = fmaf(wj3, (float)v[3], a3);
        }
    }
    a0 = a0 / (1.f + __expf(-a0));
    a1 = a1 / (1.f + __expf(-a1));
    a2 = a2 / (1.f + __expf(-a2));
    a3 = a3 / (1.f + __expf(-a3));
    bf16x4 ob;
    ob[0] = (__bf16)a0; ob[1] = (__bf16)a1; ob[2] = (__bf16)a2; ob[3] = (__bf16)a3;
    *(bf16x4*)(xsc + (size_t)m * D_INNER + d) = ob;
}

// ---------------------------------------------------------------------------
// Chunked SSM scan + D skip + gate (unchanged).
// ---------------------------------------------------------------------------
__global__ __launch_bounds__(256) void ssm_scan(
    const __bf16* __restrict__ xsc, const float* __restrict__ bc,
    const __bf16* __restrict__ szbf, __bf16* __restrict__ ybf,
    const float* __restrict__ alog, const float* __restrict__ dpar)
{
    __shared__ float Bsh[CHUNK + WARM][16];
    __shared__ float Csh[CHUNK + WARM][16];
    __shared__ float Xsh[2][TSTEP][256];
    __shared__ float Zsh[2][TSTEP][256];

    const int tid = threadIdx.x;
    const int blk = blockIdx.x;
    const int db  = blk & 7;
    const int ch  = (blk >> 3) & (NCHUNK - 1);
    const int b   = blk >> 8;
    const int d0  = db * 256;
    const int d   = d0 + tid;
    const int t0  = ch * CHUNK;
    const int tw  = (t0 >= WARM) ? (t0 - WARM) : 0;
    const int warm = t0 - tw;
    const int nt  = t0 + CHUNK - tw;
    const int ntiles = nt / TSTEP;

    const float* bcp = bc + ((size_t)b * SEQ + tw) * 32;
    for (int i = tid; i < nt * 8; i += 256) {
        const int row = i >> 3, q = i & 7;
        const float4 v = *(const float4*)(bcp + (size_t)row * 32 + q * 4);
        if (q < 4) *(float4*)&Bsh[row][q * 4] = v;
        else       *(float4*)&Csh[row][(q - 4) * 4] = v;
    }

    float dAv[16], h[16];
    #pragma unroll
    for (int q = 0; q < 4; ++q) {
        const float4 av = *(const float4*)(alog + (size_t)d * D_STATE + q * 4);
        dAv[q*4+0] = expf(-DT_VAL * expf(av.x));
        dAv[q*4+1] = expf(-DT_VAL * expf(av.y));
        dAv[q*4+2] = expf(-DT_VAL * expf(av.z));
        dAv[q*4+3] = expf(-DT_VAL * expf(av.w));
    }
    #pragma unroll
    for (int n = 0; n < 16; ++n) h[n] = 0.f;
    const float Dd = dpar[d];

    const __bf16* xbase = xsc  + ((size_t)b * SEQ + tw) * D_INNER + d0;
    const __bf16* zbase = szbf + ((size_t)b * SEQ + tw) * D_INNER + d0;
    __bf16*       ybase = ybf  + ((size_t)b * SEQ + tw) * D_INNER + d0;

    const int lrow = tid >> 6;
    const int lcol = (tid & 63) << 2;

    {
        const bf16x4 xa = *(const bf16x4*)(xbase + (size_t)lrow * D_INNER + lcol);
        const bf16x4 xb = *(const bf16x4*)(xbase + (size_t)(lrow + 4) * D_INNER + lcol);
        float4 fa, fb;
        fa.x=(float)xa[0]; fa.y=(float)xa[1]; fa.z=(float)xa[2]; fa.w=(float)xa[3];
        fb.x=(float)xb[0]; fb.y=(float)xb[1]; fb.z=(float)xb[2]; fb.w=(float)xb[3];
        *(float4*)&Xsh[0][lrow][lcol]     = fa;
        *(float4*)&Xsh[0][lrow + 4][lcol] = fb;
        if (warm == 0) {
            const bf16x4 za = *(const bf16x4*)(zbase + (size_t)lrow * D_INNER + lcol);
            const bf16x4 zb = *(const bf16x4*)(zbase + (size_t)(lrow + 4) * D_INNER + lcol);
            float4 ga, gb;
            ga.x=(float)za[0]; ga.y=(float)za[1]; ga.z=(float)za[2]; ga.w=(float)za[3];
            gb.x=(float)zb[0]; gb.y=(float)zb[1]; gb.z=(float)zb[2]; gb.w=(float)zb[3];
            *(float4*)&Zsh[0][lrow][lcol]     = ga;
            *(float4*)&Zsh[0][lrow + 4][lcol] = gb;
        }
    }
    __syncthreads();

    for (int tile = 0; tile < ntiles; ++tile) {
        const int buf = tile & 1;
        const int s   = tile * TSTEP;
        const int s2  = s + TSTEP;
        const bool more = (tile + 1 < ntiles);
        const bool znext = more && (s2 >= warm);

        bf16x4 rx0, rx1, rz0, rz1;
        if (more) {
            rx0 = *(const bf16x4*)(xbase + (size_t)(s2 + lrow) * D_INNER + lcol);
            rx1 = *(const bf16x4*)(xbase + (size_t)(s2 + lrow + 4) * D_INNER + lcol);
        }
        if (znext) {
            rz0 = *(const bf16x4*)(zbase + (size_t)(s2 + lrow) * D_INNER + lcol);
            rz1 = *(const bf16x4*)(zbase + (size_t)(s2 + lrow + 4) * D_INNER + lcol);
        }

        #pragma unroll
        for (int tt = 0; tt < TSTEP; ++tt) {
            const int t = s + tt;
            const float x   = Xsh[buf][tt][tid];
            const float dtx = DT_VAL * x;
            float y0 = 0.f, y1 = 0.f, y2 = 0.f, y3 = 0.f;
            #pragma unroll
            for (int n = 0; n < 4; ++n) {
                h[n]      = fmaf(dAv[n],      h[n],      dtx * Bsh[t][n]);
                h[n + 4]  = fmaf(dAv[n + 4],  h[n + 4],  dtx * Bsh[t][n + 4]);
                h[n + 8]  = fmaf(dAv[n + 8],  h[n + 8],  dtx * Bsh[t][n + 8]);
                h[n + 12] = fmaf(dAv[n + 12], h[n + 12], dtx * Bsh[t][n + 12]);
                y0 = fmaf(h[n],      Csh[t][n],      y0);
                y1 = fmaf(h[n + 4],  Csh[t][n + 4],  y1);
                y2 = fmaf(h[n + 8],  Csh[t][n + 8],  y2);
                y3 = fmaf(h[n + 12], Csh[t][n + 12], y3);
            }
            if (t >= warm) {
                const float sz = Zsh[buf][tt][tid];
                const float y  = fmaf(x, Dd, (y0 + y1) + (y2 + y3));
                ybase[(size_t)t * D_INNER + tid] = (__bf16)(y * sz);
            }
        }

        if (more) {
            float4 fa, fb;
            fa.x=(float)rx0[0]; fa.y=(float)rx0[1]; fa.z=(float)rx0[2]; fa.w=(float)rx0[3];
            fb.x=(float)rx1[0]; fb.y=(float)rx1[1]; fb.z=(float)rx1[2]; fb.w=(float)rx1[3];
            *(float4*)&Xsh[buf ^ 1][lrow][lcol]     = fa;
            *(float4*)&Xsh[buf ^ 1][lrow + 4][lcol] = fb;
        }
        if (znext) {
            float4 ga, gb;
            ga.x=(float)rz0[0]; ga.y=(float)rz0[1]; ga.z=(float)rz0[2]; ga.w=(float)rz0[3];
            gb.x=(float)rz1[0]; gb.y=(float)rz1[1]; gb.z=(float)rz1[2]; gb.w=(float)rz1[3];
            *(float4*)&Zsh[buf ^ 1][lrow][lcol]     = ga;
            *(float4*)&Zsh[buf ^ 1][lrow + 4][lcol] = gb;
        }
        __syncthreads();
    }
}

// ---------------------------------------------------------------------------
extern "C" void kernel_launch(void* const* d_in, const int* in_sizes, int n_in,
                              void* d_out, int out_size, void* d_ws, size_t ws_size,
                              hipStream_t stream)
{
    const float* x    = (const float*)d_in[0];
    const float* win  = (const float*)d_in[1];
    const float* cw   = (const float*)d_in[2];
    const float* cb   = (const float*)d_in[3];
    const float* xpw  = (const float*)d_in[4];
    const float* alog = (const float*)d_in[5];
    const float* dpar = (const float*)d_in[6];
    const float* wout = (const float*)d_in[7];
    float* out = (float*)d_out;

    char* w = (char*)d_ws;
    float*  pbuf   = (float*)w;                   // split-K slices 0,1 (33.5 MB)
    __bf16* szbf   = (__bf16*)(w + 33554432);     // 4096x2048 bf16
    __bf16* xspbf  = (__bf16*)(w + 50331648);     // 4096x2048 bf16 (dead after conv)
    __bf16* xsc    = (__bf16*)(w + 67108864);     // 4096x2048 bf16 (dead after scan)
    float*  pbuf2  = (float*)(w + 50331648);      // split-K slices 2,3 (reuses xspbf+xsc)
    float*  bcbuf  = (float*)(w + 83886080);      // 4096x32 f32
    __bf16* r1     = (__bf16*)(w + 84410368);     // 16.8 MB region
    __bf16* xbf    = r1;
    __bf16* winbf  = r1 + 4194304;
    __bf16* ybf    = r1;                          // reuse after in_proj
    __bf16* woutbf = (__bf16*)(w + 101187584);
    __bf16* xpwbf  = (__bf16*)(w + 105381888);

    // 0) cast inputs/weights to bf16 + zero bcbuf (fused)
    cast5<<<10432, 256, 0, stream>>>(x, win, wout, xpw,
                                     xbf, winbf, woutbf, xpwbf, bcbuf);
    // 1) in_proj: xspbf = bf16(x@win^T)[:,:2048], szbf = bf16(silu half)
    gemm_v6<1, 1024, 1024, 1024, 32><<<1024, 256, 0, stream>>>(
        xbf, winbf, nullptr, nullptr, 0, xspbf, szbf);
    // 2) causal depthwise conv + SiLU -> xsc (bf16)
    conv_silu<<<(M_TOTAL * (D_INNER / 4)) / 256, 256, 0, stream>>>(
        xspbf, cw, cb, xsc);
    // 3) x_proj (MFMA, split-K=8): bc += xsc @ xpwbf^T
    xproj_mfma<<<256, 256, 0, stream>>>(xsc, xpwbf, bcbuf);
    // 4) chunked scan + D skip + gate -> ybf (bf16)
    ssm_scan<<<BATCH * NCHUNK * 8, 256, 0, stream>>>(
        xsc, bcbuf, szbf, ybf, alog, dpar);
    // 5) out_proj split-K=4 into partials (slices 2,3 in dead xspbf/xsc space)
    gemm_v6<2, 2048, 2048, 512, 8><<<1024, 256, 0, stream>>>(
        ybf, woutbf, pbuf, pbuf2, D_MODEL, nullptr, nullptr);
    reduce4<<<(M_TOTAL * D_MODEL / 4) / 256, 256, 0, stream>>>(pbuf, pbuf2, out);
}

// Round 11
// 238.346 us; speedup vs baseline: 1.1596x; 1.1596x over previous
//
#include <hip/hip_runtime.h>
#include <hip/hip_bf16.h>
#include <math.h>

#define D_MODEL 1024
#define D_STATE 16
#define D_CONV  4
#define D_INNER 2048
#define BATCH   2
#define SEQ     2048
#define M_TOTAL (BATCH*SEQ)   // 4096
#define DT_VAL  0.1f

// scan chunking: 32 chunks of 64 outputs, 64 warmup steps (dA^64 <= 1.7e-3)
#define CHUNK 64
#define WARM  64
#define NCHUNK (SEQ / CHUNK)  // 32
#define TSTEP 8               // x/z tile depth staged through LDS

typedef __attribute__((ext_vector_type(8))) __bf16 bf16x8;
typedef __attribute__((ext_vector_type(4))) __bf16 bf16x4;
typedef __attribute__((ext_vector_type(4))) float floatx4;

// async global->LDS, 16 B per lane. LDS dest must be uniform base + lane*16B
// (our grow/gcol order satisfies this per 32-wide panel; see m97/m104 notes).
__device__ __forceinline__ void gld_lds16(const __bf16* g, __bf16* l) {
    __builtin_amdgcn_global_load_lds(
        (const __attribute__((address_space(1))) void*)g,
        (__attribute__((address_space(3))) void*)l, 16, 0, 0);
}

// ---------------------------------------------------------------------------
// NT GEMM, bf16 inputs: C[m][n] = sum_k A[m][k]*W[n][k].  (round-9 verified)
// 128x128 tile, BK=64 as two 32-wide panels: issue all 8 async loads, one
// drain, 32 MFMAs. K-loop pipelining experiments (r10 single-barrier dbuf)
// REGRESSED 57->68 us — do not re-try; m99/m100 say the same.
// Strides/extents are template constants (strength-reduced addressing).
// Block swizzle: bid&7 = XCD group -> 4 consecutive M-stripes (L2 reuse).
// EPI 1 (in_proj): n0<2048 -> O1 = bf16(acc); n0>=2048 -> O2 = bf16(silu(acc)).
// EPI 2 (out_proj, split-K=4): plain stores; ks 0,1 -> Cf, ks 2,3 -> Cf2.
// Occupancy note: 32 KB LDS + ~88 VGPR keeps 4+ blocks/CU (round-8 fat tile
// at 48 KB/168 VGPR regressed 60->93 us — occupancy beats per-block reuse).
// ---------------------------------------------------------------------------
template<int EPI, int LDA, int LDW, int KLEN, int NBX>
__global__ __launch_bounds__(256) void gemm_v5(
    const __bf16* __restrict__ A, const __bf16* __restrict__ W,
    float* __restrict__ Cf, float* __restrict__ Cf2, int ldc,
    __bf16* __restrict__ O1, __bf16* __restrict__ O2)
{
    __shared__ __bf16 As[2][128][32];   // 16 KB (two k-panels)
    __shared__ __bf16 Bs[2][128][32];   // 16 KB

    const int tid  = threadIdx.x;
    const int bid  = blockIdx.x;
    const int xcd  = bid & 7;
    const int i    = bid >> 3;
    const int byl  = i & 3;
    const int rest = i >> 2;
    const int bx   = rest % NBX;
    const int ks   = rest / NBX;
    const int m0   = (xcd * 4 + byl) * 128;
    const int n0   = bx * 128;
    const int koff = ks * KLEN;

    const int wave = tid >> 6;
    const int lane = tid & 63;
    const int wr   = (wave >> 1) << 6;
    const int wc   = (wave & 1) << 6;
    const int fm   = lane & 15;
    const int fk   = (lane >> 4) << 3;
    const int grow = lane >> 2;
    const int gcol = (lane & 3) << 3;
    const int arow = wave * 16 + grow;

    floatx4 acc[4][4];
    #pragma unroll
    for (int a = 0; a < 4; ++a)
        #pragma unroll
        for (int b = 0; b < 4; ++b)
            acc[a][b] = (floatx4){0.f, 0.f, 0.f, 0.f};

    const __bf16* ap = A + (size_t)(m0 + arow) * LDA + koff + gcol;
    const __bf16* wp = W + (size_t)(n0 + arow) * LDW + koff + gcol;

    for (int k0 = 0; k0 < KLEN; k0 += 64) {
        __syncthreads();   // protect LDS from previous iteration's readers
        #pragma unroll
        for (int p = 0; p < 2; ++p) {
            gld_lds16(ap + k0 + p * 32,                    &As[p][arow][gcol]);
            gld_lds16(ap + k0 + p * 32 + (size_t)64 * LDA, &As[p][arow + 64][gcol]);
            gld_lds16(wp + k0 + p * 32,                    &Bs[p][arow][gcol]);
            gld_lds16(wp + k0 + p * 32 + (size_t)64 * LDW, &Bs[p][arow + 64][gcol]);
        }
        __syncthreads();   // drains vmcnt (global_load_lds) before reads

        #pragma unroll
        for (int p = 0; p < 2; ++p) {
            bf16x8 af[4], bfv[4];
            #pragma unroll
            for (int a = 0; a < 4; ++a)
                af[a] = *(bf16x8*)&As[p][wr + a * 16 + fm][fk];
            #pragma unroll
            for (int b = 0; b < 4; ++b)
                bfv[b] = *(bf16x8*)&Bs[p][wc + b * 16 + fm][fk];
            #pragma unroll
            for (int a = 0; a < 4; ++a)
                #pragma unroll
                for (int b = 0; b < 4; ++b)
                    acc[a][b] = __builtin_amdgcn_mfma_f32_16x16x32_bf16(
                        af[a], bfv[b], acc[a][b], 0, 0, 0);
        }
    }

    // epilogue: C/D layout col=lane&15, row=(lane>>4)*4+reg
    const int crow = (lane >> 4) << 2;
    const int ccol = lane & 15;
    #pragma unroll
    for (int a = 0; a < 4; ++a) {
        #pragma unroll
        for (int b = 0; b < 4; ++b) {
            const int cm = m0 + wr + a * 16 + crow;
            const int cn = n0 + wc + b * 16 + ccol;
            #pragma unroll
            for (int r = 0; r < 4; ++r) {
                const float v = acc[a][b][r];
                if (EPI == 1) {
                    if (n0 < 2048) {
                        O1[(size_t)(cm + r) * 2048 + cn] = (__bf16)v;
                    } else {
                        const float s = v / (1.f + __expf(-v));
                        O2[(size_t)(cm + r) * 2048 + cn - 2048] = (__bf16)s;
                    }
                } else {
                    float* dst = (ks < 2 ? Cf : Cf2) +
                                 (size_t)(ks & 1) * M_TOTAL * ldc;
                    dst[(size_t)(cm + r) * ldc + cn] = v;
                }
            }
        }
    }
}

// ---------------------------------------------------------------------------
// Reduce split-K=4 partials: out = (p0+p1) + (p2+p3).
// ---------------------------------------------------------------------------
__global__ __launch_bounds__(256) void reduce4(
    const float* __restrict__ p01, const float* __restrict__ p23,
    float* __restrict__ out)
{
    const size_t i = (size_t)(blockIdx.x * 256 + threadIdx.x) * 4;
    const float4 a = *(const float4*)(p01 + i);
    const float4 b = *(const float4*)(p01 + (size_t)M_TOTAL * D_MODEL + i);
    const float4 c = *(const float4*)(p23 + i);
    const float4 d = *(const float4*)(p23 + (size_t)M_TOTAL * D_MODEL + i);
    float4 o;
    o.x = (a.x + b.x) + (c.x + d.x);
    o.y = (a.y + b.y) + (c.y + d.y);
    o.z = (a.z + b.z) + (c.z + d.z);
    o.w = (a.w + b.w) + (c.w + d.w);
    *(float4*)(out + i) = o;
}

// ---------------------------------------------------------------------------
// x_proj as MFMA GEMM: bc[m][j] += sum_k xsc[m][k] * wp[j][k], j in 0..31.
// 128-row m-tile, split-K=8 (k-chunk 256), 32x8 = 256 blocks.
// ---------------------------------------------------------------------------
__global__ __launch_bounds__(256) void xproj_mfma(
    const __bf16* __restrict__ X, const __bf16* __restrict__ Wp,
    float* __restrict__ bc)
{
    __shared__ __bf16 Ash[128][32];    // 8 KB, unpadded
    __shared__ __bf16 Wsh[32][264];    // 16.5 KB; stride 264 -> 2-way max

    const int tid  = threadIdx.x;
    const int bid  = blockIdx.x;
    const int ks   = bid & 7;
    const int mb   = bid >> 3;
    const int m0   = mb * 128;
    const int koff = ks * 256;
    const int wave = tid >> 6;
    const int lane = tid & 63;
    const int fm   = lane & 15;
    const int fk   = (lane >> 4) << 3;
    const int grow = lane >> 2;
    const int gcol = (lane & 3) << 3;

    {
        const int r = tid >> 3;
        const int c = (tid & 7) << 5;
        #pragma unroll
        for (int q = 0; q < 4; ++q)
            *(bf16x8*)&Wsh[r][c + q * 8] =
                *(const bf16x8*)(Wp + (size_t)r * D_INNER + koff + c + q * 8);
    }

    floatx4 acc[2][2];
    #pragma unroll
    for (int a = 0; a < 2; ++a)
        #pragma unroll
        for (int b = 0; b < 2; ++b)
            acc[a][b] = (floatx4){0.f, 0.f, 0.f, 0.f};

    for (int kit = 0; kit < 8; ++kit) {
        const int kg = koff + kit * 32;
        __syncthreads();
        #pragma unroll
        for (int issue = 0; issue < 2; ++issue) {
            const int r = issue * 64 + wave * 16 + grow;
            gld_lds16(X + (size_t)(m0 + r) * D_INNER + kg + gcol, &Ash[r][gcol]);
        }
        __syncthreads();

        bf16x8 af[2], wf[2];
        af[0] = *(bf16x8*)&Ash[wave * 32 + fm][fk];
        af[1] = *(bf16x8*)&Ash[wave * 32 + 16 + fm][fk];
        wf[0] = *(bf16x8*)&Wsh[fm][kit * 32 + fk];
        wf[1] = *(bf16x8*)&Wsh[16 + fm][kit * 32 + fk];
        #pragma unroll
        for (int a = 0; a < 2; ++a)
            #pragma unroll
            for (int b = 0; b < 2; ++b)
                acc[a][b] = __builtin_amdgcn_mfma_f32_16x16x32_bf16(
                    af[a], wf[b], acc[a][b], 0, 0, 0);
    }

    const int crow = (lane >> 4) << 2;
    const int ccol = lane & 15;
    #pragma unroll
    for (int a = 0; a < 2; ++a)
        #pragma unroll
        for (int b = 0; b < 2; ++b)
            #pragma unroll
            for (int r = 0; r < 4; ++r)
                atomicAdd(bc + (size_t)(m0 + wave * 32 + a * 16 + crow + r) * 32
                             + b * 16 + ccol, acc[a][b][r]);
}

// ---------------------------------------------------------------------------
// Cast x, in_proj_w, out_proj_w, x_proj_w to bf16 AND zero bcbuf, one kernel.
// ---------------------------------------------------------------------------
__global__ __launch_bounds__(256) void cast5(
    const float* __restrict__ x, const float* __restrict__ win,
    const float* __restrict__ wout, const float* __restrict__ xpw,
    __bf16* __restrict__ xbf, __bf16* __restrict__ winbf,
    __bf16* __restrict__ woutbf, __bf16* __restrict__ xpwbf,
    float* __restrict__ bcz)
{
    const size_t g = (size_t)(blockIdx.x * 256 + threadIdx.x);
    if (g >= 2637824) {   // zero segment: bcbuf (131072 floats)
        const size_t off = (g - 2637824) * 4;
        *(float4*)(bcz + off) = (float4){0.f, 0.f, 0.f, 0.f};
        return;
    }
    const size_t j = g * 4;
    const float* src; __bf16* dst; size_t off;
    if (j < 4194304)       { src = x;    dst = xbf;    off = j; }
    else if (j < 8388608)  { src = win;  dst = winbf;  off = j - 4194304; }
    else if (j < 10485760) { src = wout; dst = woutbf; off = j - 8388608; }
    else                   { src = xpw;  dst = xpwbf;  off = j - 10485760; }
    const float4 v = *(const float4*)(src + off);
    bf16x4 o;
    o[0] = (__bf16)v.x; o[1] = (__bf16)v.y; o[2] = (__bf16)v.z; o[3] = (__bf16)v.w;
    *(bf16x4*)(dst + off) = o;
}

// ---------------------------------------------------------------------------
// Depthwise causal conv (k=4) + bias + SiLU, time-blocked: one thread per
// (4 d, 4 consecutive t) -> 7 row-loads for 4 outputs (was 4 loads / 1 out).
// Rows t-3..t+3 stay within batch b iff guarded by l>=3 at sequence start.
// ---------------------------------------------------------------------------
__global__ __launch_bounds__(256) void conv_silu4(
    const __bf16* __restrict__ xsp, const float* __restrict__ cw,
    const float* __restrict__ cb, __bf16* __restrict__ xsc)
{
    const int g    = blockIdx.x * 256 + threadIdx.x;   // 512 dgroups x 1024 tblocks
    const int d4   = g & (D_INNER / 4 - 1);
    const int mblk = g >> 9;                            // 0..1023
    const int m0   = mblk << 2;                         // first t of this block
    const int d    = d4 << 2;

    const float4 w0 = *(const float4*)(cw + (size_t)(d + 0) * 4);
    const float4 w1 = *(const float4*)(cw + (size_t)(d + 1) * 4);
    const float4 w2 = *(const float4*)(cw + (size_t)(d + 2) * 4);
    const float4 w3 = *(const float4*)(cw + (size_t)(d + 3) * 4);
    const float4 bv = *(const float4*)(cb + d);

    // load rows m0-3 .. m0+3 (7 rows); row j valid iff (m0&2047)+j >= 3
    float4 rows[7];
    const int lbase = m0 & (SEQ - 1);
    #pragma unroll
    for (int j = 0; j < 7; ++j) {
        if (lbase + j >= 3) {
            const bf16x4 v = *(const bf16x4*)(xsp + (size_t)(m0 + j - 3) * D_INNER + d);
            rows[j].x = (float)v[0]; rows[j].y = (float)v[1];
            rows[j].z = (float)v[2]; rows[j].w = (float)v[3];
        } else {
            rows[j] = (float4){0.f, 0.f, 0.f, 0.f};
        }
    }

    #pragma unroll
    for (int o = 0; o < 4; ++o) {       // output t = m0 + o, taps rows[o..o+3]
        float a0 = bv.x, a1 = bv.y, a2 = bv.z, a3 = bv.w;
        #pragma unroll
        for (int j = 0; j < 4; ++j) {
            const float4 v = rows[o + j];
            const float wj0 = (j==0)?w0.x:(j==1)?w0.y:(j==2)?w0.z:w0.w;
            const float wj1 = (j==0)?w1.x:(j==1)?w1.y:(j==2)?w1.z:w1.w;
            const float wj2 = (j==0)?w2.x:(j==1)?w2.y:(j==2)?w2.z:w2.w;
            const float wj3 = (j==0)?w3.x:(j==1)?w3.y:(j==2)?w3.z:w3.w;
            a0 = fmaf(wj0, v.x, a0);
            a1 = fmaf(wj1, v.y, a1);
            a2 = fmaf(wj2, v.z, a2);
            a3 = fmaf(wj3, v.w, a3);
        }
        a0 = a0 / (1.f + __expf(-a0));
        a1 = a1 / (1.f + __expf(-a1));
        a2 = a2 / (1.f + __expf(-a2));
        a3 = a3 / (1.f + __expf(-a3));
        bf16x4 ob;
        ob[0] = (__bf16)a0; ob[1] = (__bf16)a1;
        ob[2] = (__bf16)a2; ob[3] = (__bf16)a3;
        *(bf16x4*)(xsc + (size_t)(m0 + o) * D_INNER + d) = ob;
    }
}

// ---------------------------------------------------------------------------
// Chunked SSM scan + D skip + gate (unchanged).
// ---------------------------------------------------------------------------
__global__ __launch_bounds__(256) void ssm_scan(
    const __bf16* __restrict__ xsc, const float* __restrict__ bc,
    const __bf16* __restrict__ szbf, __bf16* __restrict__ ybf,
    const float* __restrict__ alog, const float* __restrict__ dpar)
{
    __shared__ float Bsh[CHUNK + WARM][16];
    __shared__ float Csh[CHUNK + WARM][16];
    __shared__ float Xsh[2][TSTEP][256];
    __shared__ float Zsh[2][TSTEP][256];

    const int tid = threadIdx.x;
    const int blk = blockIdx.x;
    const int db  = blk & 7;
    const int ch  = (blk >> 3) & (NCHUNK - 1);
    const int b   = blk >> 8;
    const int d0  = db * 256;
    const int d   = d0 + tid;
    const int t0  = ch * CHUNK;
    const int tw  = (t0 >= WARM) ? (t0 - WARM) : 0;
    const int warm = t0 - tw;
    const int nt  = t0 + CHUNK - tw;
    const int ntiles = nt / TSTEP;

    const float* bcp = bc + ((size_t)b * SEQ + tw) * 32;
    for (int i = tid; i < nt * 8; i += 256) {
        const int row = i >> 3, q = i & 7;
        const float4 v = *(const float4*)(bcp + (size_t)row * 32 + q * 4);
        if (q < 4) *(float4*)&Bsh[row][q * 4] = v;
        else       *(float4*)&Csh[row][(q - 4) * 4] = v;
    }

    float dAv[16], h[16];
    #pragma unroll
    for (int q = 0; q < 4; ++q) {
        const float4 av = *(const float4*)(alog + (size_t)d * D_STATE + q * 4);
        dAv[q*4+0] = expf(-DT_VAL * expf(av.x));
        dAv[q*4+1] = expf(-DT_VAL * expf(av.y));
        dAv[q*4+2] = expf(-DT_VAL * expf(av.z));
        dAv[q*4+3] = expf(-DT_VAL * expf(av.w));
    }
    #pragma unroll
    for (int n = 0; n < 16; ++n) h[n] = 0.f;
    const float Dd = dpar[d];

    const __bf16* xbase = xsc  + ((size_t)b * SEQ + tw) * D_INNER + d0;
    const __bf16* zbase = szbf + ((size_t)b * SEQ + tw) * D_INNER + d0;
    __bf16*       ybase = ybf  + ((size_t)b * SEQ + tw) * D_INNER + d0;

    const int lrow = tid >> 6;
    const int lcol = (tid & 63) << 2;

    {
        const bf16x4 xa = *(const bf16x4*)(xbase + (size_t)lrow * D_INNER + lcol);
        const bf16x4 xb = *(const bf16x4*)(xbase + (size_t)(lrow + 4) * D_INNER + lcol);
        float4 fa, fb;
        fa.x=(float)xa[0]; fa.y=(float)xa[1]; fa.z=(float)xa[2]; fa.w=(float)xa[3];
        fb.x=(float)xb[0]; fb.y=(float)xb[1]; fb.z=(float)xb[2]; fb.w=(float)xb[3];
        *(float4*)&Xsh[0][lrow][lcol]     = fa;
        *(float4*)&Xsh[0][lrow + 4][lcol] = fb;
        if (warm == 0) {
            const bf16x4 za = *(const bf16x4*)(zbase + (size_t)lrow * D_INNER + lcol);
            const bf16x4 zb = *(const bf16x4*)(zbase + (size_t)(lrow + 4) * D_INNER + lcol);
            float4 ga, gb;
            ga.x=(float)za[0]; ga.y=(float)za[1]; ga.z=(float)za[2]; ga.w=(float)za[3];
            gb.x=(float)zb[0]; gb.y=(float)zb[1]; gb.z=(float)zb[2]; gb.w=(float)zb[3];
            *(float4*)&Zsh[0][lrow][lcol]     = ga;
            *(float4*)&Zsh[0][lrow + 4][lcol] = gb;
        }
    }
    __syncthreads();

    for (int tile = 0; tile < ntiles; ++tile) {
        const int buf = tile & 1;
        const int s   = tile * TSTEP;
        const int s2  = s + TSTEP;
        const bool more = (tile + 1 < ntiles);
        const bool znext = more && (s2 >= warm);

        bf16x4 rx0, rx1, rz0, rz1;
        if (more) {
            rx0 = *(const bf16x4*)(xbase + (size_t)(s2 + lrow) * D_INNER + lcol);
            rx1 = *(const bf16x4*)(xbase + (size_t)(s2 + lrow + 4) * D_INNER + lcol);
        }
        if (znext) {
            rz0 = *(const bf16x4*)(zbase + (size_t)(s2 + lrow) * D_INNER + lcol);
            rz1 = *(const bf16x4*)(zbase + (size_t)(s2 + lrow + 4) * D_INNER + lcol);
        }

        #pragma unroll
        for (int tt = 0; tt < TSTEP; ++tt) {
            const int t = s + tt;
            const float x   = Xsh[buf][tt][tid];
            const float dtx = DT_VAL * x;
            float y0 = 0.f, y1 = 0.f, y2 = 0.f, y3 = 0.f;
            #pragma unroll
            for (int n = 0; n < 4; ++n) {
                h[n]      = fmaf(dAv[n],      h[n],      dtx * Bsh[t][n]);
                h[n + 4]  = fmaf(dAv[n + 4],  h[n + 4],  dtx * Bsh[t][n + 4]);
                h[n + 8]  = fmaf(dAv[n + 8],  h[n + 8],  dtx * Bsh[t][n + 8]);
                h[n + 12] = fmaf(dAv[n + 12], h[n + 12], dtx * Bsh[t][n + 12]);
                y0 = fmaf(h[n],      Csh[t][n],      y0);
                y1 = fmaf(h[n + 4],  Csh[t][n + 4],  y1);
                y2 = fmaf(h[n + 8],  Csh[t][n + 8],  y2);
                y3 = fmaf(h[n + 12], Csh[t][n + 12], y3);
            }
            if (t >= warm) {
                const float sz = Zsh[buf][tt][tid];
                const float y  = fmaf(x, Dd, (y0 + y1) + (y2 + y3));
                ybase[(size_t)t * D_INNER + tid] = (__bf16)(y * sz);
            }
        }

        if (more) {
            float4 fa, fb;
            fa.x=(float)rx0[0]; fa.y=(float)rx0[1]; fa.z=(float)rx0[2]; fa.w=(float)rx0[3];
            fb.x=(float)rx1[0]; fb.y=(float)rx1[1]; fb.z=(float)rx1[2]; fb.w=(float)rx1[3];
            *(float4*)&Xsh[buf ^ 1][lrow][lcol]     = fa;
            *(float4*)&Xsh[buf ^ 1][lrow + 4][lcol] = fb;
        }
        if (znext) {
            float4 ga, gb;
            ga.x=(float)rz0[0]; ga.y=(float)rz0[1]; ga.z=(float)rz0[2]; ga.w=(float)rz0[3];
            gb.x=(float)rz1[0]; gb.y=(float)rz1[1]; gb.z=(float)rz1[2]; gb.w=(float)rz1[3];
            *(float4*)&Zsh[buf ^ 1][lrow][lcol]     = ga;
            *(float4*)&Zsh[buf ^ 1][lrow + 4][lcol] = gb;
        }
        __syncthreads();
    }
}

// ---------------------------------------------------------------------------
extern "C" void kernel_launch(void* const* d_in, const int* in_sizes, int n_in,
                              void* d_out, int out_size, void* d_ws, size_t ws_size,
                              hipStream_t stream)
{
    const float* x    = (const float*)d_in[0];
    const float* win  = (const float*)d_in[1];
    const float* cw   = (const float*)d_in[2];
    const float* cb   = (const float*)d_in[3];
    const float* xpw  = (const float*)d_in[4];
    const float* alog = (const float*)d_in[5];
    const float* dpar = (const float*)d_in[6];
    const float* wout = (const float*)d_in[7];
    float* out = (float*)d_out;

    char* w = (char*)d_ws;
    float*  pbuf   = (float*)w;                   // split-K slices 0,1 (33.5 MB)
    __bf16* szbf   = (__bf16*)(w + 33554432);     // 4096x2048 bf16
    __bf16* xspbf  = (__bf16*)(w + 50331648);     // 4096x2048 bf16 (dead after conv)
    __bf16* xsc    = (__bf16*)(w + 67108864);     // 4096x2048 bf16 (dead after scan)
    float*  pbuf2  = (float*)(w + 50331648);      // split-K slices 2,3 (reuses xspbf+xsc)
    float*  bcbuf  = (float*)(w + 83886080);      // 4096x32 f32
    __bf16* r1     = (__bf16*)(w + 84410368);     // 16.8 MB region
    __bf16* xbf    = r1;
    __bf16* winbf  = r1 + 4194304;
    __bf16* ybf    = r1;                          // reuse after in_proj
    __bf16* woutbf = (__bf16*)(w + 101187584);
    __bf16* xpwbf  = (__bf16*)(w + 105381888);

    // 0) cast inputs/weights to bf16 + zero bcbuf (fused)
    cast5<<<10432, 256, 0, stream>>>(x, win, wout, xpw,
                                     xbf, winbf, woutbf, xpwbf, bcbuf);
    // 1) in_proj: xspbf = bf16(x@win^T)[:,:2048], szbf = bf16(silu half)
    gemm_v5<1, 1024, 1024, 1024, 32><<<1024, 256, 0, stream>>>(
        xbf, winbf, nullptr, nullptr, 0, xspbf, szbf);
    // 2) causal depthwise conv + SiLU -> xsc (bf16), time-blocked x4
    conv_silu4<<<(M_TOTAL / 4 * (D_INNER / 4)) / 256, 256, 0, stream>>>(
        xspbf, cw, cb, xsc);
    // 3) x_proj (MFMA, split-K=8): bc += xsc @ xpwbf^T
    xproj_mfma<<<256, 256, 0, stream>>>(xsc, xpwbf, bcbuf);
    // 4) chunked scan + D skip + gate -> ybf (bf16)
    ssm_scan<<<BATCH * NCHUNK * 8, 256, 0, stream>>>(
        xsc, bcbuf, szbf, ybf, alog, dpar);
    // 5) out_proj split-K=4 into partials (slices 2,3 in dead xspbf/xsc space)
    gemm_v5<2, 2048, 2048, 512, 8><<<1024, 256, 0, stream>>>(
        ybf, woutbf, pbuf, pbuf2, D_MODEL, nullptr, nullptr);
    reduce4<<<(M_TOTAL * D_MODEL / 4) / 256, 256, 0, stream>>>(pbuf, pbuf2, out);
}